// Round 4
// baseline (495.197 us; speedup 1.0000x reference)
//
#include <hip/hip_runtime.h>
#include <cstdint>
#include <cstddef>

#define NN    8192      // N
#define NIN   4096      // N_IN
#define BB    16        // B
#define BN    131072    // B*N
#define ROWCH 512       // rows per chunk
#define NCHI  16        // int chunks  (8192/512)
#define NCHE  8         // ext chunks  (4096/512)
#define NCH   24        // total chunks

static constexpr float ALPHA_F = 0.9512294245007140f;               // fl32(exp(-0.05))
static constexpr float RHOA_F  = 0.9950124791926823f;               // fl32(exp(-0.005))
static constexpr float SCALE_F = (float)(1.0 - 0.9512294245007140); // fl32(1 - alpha)

// ---------------------------------------------------------------------------
// k_aux: (a) per-row spike bit-masks from Xd[-1] / Xext, (b) delay-buffer
// shift Xd_new[1:8] = Xd[0:7] (float4).
// ---------------------------------------------------------------------------
__global__ __launch_bounds__(256) void k_aux(
    const float* __restrict__ Xd, const float* __restrict__ Xext,
    float* __restrict__ out,
    unsigned* __restrict__ mask_int, unsigned* __restrict__ mask_ext)
{
    const int t = blockIdx.x * 256 + threadIdx.x;   // [0, 7*BN/4)

    if (t < NN) {                       // internal mask from Xd[-1]
        unsigned m = 0;
        #pragma unroll
        for (int b = 0; b < BB; ++b)
            m |= (Xd[7*BN + b*NN + t] > 0.5f) ? (1u << b) : 0u;
        mask_int[t] = m;
    } else if (t < NN + NIN) {          // external mask from Xext
        const int i = t - NN;
        unsigned m = 0;
        #pragma unroll
        for (int b = 0; b < BB; ++b)
            m |= (Xext[b*NIN + i] > 0.5f) ? (1u << b) : 0u;
        mask_ext[i] = m;
    }

    // shift: Xd_new[1:8] = Xd[0:7]
    ((float4*)(out + (size_t)4*BN))[t] = ((const float4*)Xd)[t];
}

// ---------------------------------------------------------------------------
// k_mm: spike-sparse matmul, zero-bit-skipping.
// grid = (16 col-tiles of 512, NCH chunks). Per block: compact the chunk's
// 512 masks into an active-row list, then stream rows with an 8-deep
// double-buffered load pipeline. Per row, only the ~1.43 set batch bits are
// accumulated, dispatched via a wave-uniform scalar switch (readfirstlane).
// W slice loaded ONCE per union-active row -> 225 MB HBM floor.
// ---------------------------------------------------------------------------
__device__ __forceinline__ void bitacc(float2 (&acc)[BB], unsigned e, float2 wv)
{
    unsigned ms = (unsigned)__builtin_amdgcn_readfirstlane((int)(e & 0xffffu));
    while (ms) {
        const int b = __builtin_ctz(ms);
        ms &= ms - 1u;
        switch (b) {
#define CASE_B(i) case i: acc[i].x += wv.x; acc[i].y += wv.y; break;
            CASE_B(0) CASE_B(1) CASE_B(2)  CASE_B(3)
            CASE_B(4) CASE_B(5) CASE_B(6)  CASE_B(7)
            CASE_B(8) CASE_B(9) CASE_B(10) CASE_B(11)
            CASE_B(12) CASE_B(13) CASE_B(14) CASE_B(15)
#undef CASE_B
        }
    }
}

__global__ __launch_bounds__(256) void k_mm(
    const float* __restrict__ Wint, const float* __restrict__ Wext,
    const unsigned* __restrict__ mask_int, const unsigned* __restrict__ mask_ext,
    float* __restrict__ part)
{
    const int tid  = threadIdx.x;
    const int y    = blockIdx.y;
    const int wave = tid >> 6, lane = tid & 63;
    const bool is_int = (y < NCHI);
    const float*    W    = is_int ? Wint : Wext;
    const unsigned* mask = is_int ? mask_int : mask_ext;
    const int base_row   = (is_int ? y : (y - NCHI)) * ROWCH;

    __shared__ unsigned sc[ROWCH + 8];   // compacted (localrow<<16)|mask
    __shared__ unsigned wsum[4];

    // --- per-block compaction of 512 masks (2 rounds of 256) ---
    unsigned total = 0;
    #pragma unroll
    for (int r = 0; r < 2; ++r) {
        const int idx = r * 256 + tid;
        const unsigned m = mask[base_row + idx];
        const unsigned long long bal = __ballot(m != 0);
        const unsigned pre = __popcll(bal & ((1ull << lane) - 1ull));
        if (lane == 0) wsum[wave] = (unsigned)__popcll(bal);
        __syncthreads();
        const unsigned w0 = wsum[0], w1 = wsum[1], w2 = wsum[2], w3 = wsum[3];
        unsigned bw = 0;
        if (wave > 0) bw += w0;
        if (wave > 1) bw += w1;
        if (wave > 2) bw += w2;
        if (m) sc[total + bw + pre] = ((unsigned)idx << 16) | m;
        total += w0 + w1 + w2 + w3;
        __syncthreads();
    }
    if (tid < 8) sc[total + tid] = 0u;   // zero-pad (row 0, mask 0: harmless)
    __syncthreads();
    const unsigned nrow8 = (total + 7u) & ~7u;

    const int n = (blockIdx.x << 9) + (tid << 1);   // 2 cols/thread, 512-col tile
    float2 acc[BB];
    #pragma unroll
    for (int b = 0; b < BB; ++b) acc[b] = make_float2(0.f, 0.f);

    const float* Wb = W + (size_t)base_row * NN + n;

    // --- 8-deep double-buffered stream over active rows ---
    unsigned eC[8];
    float2   wC[8];
    #pragma unroll
    for (int k = 0; k < 8; ++k) eC[k] = sc[k];
    #pragma unroll
    for (int k = 0; k < 8; ++k)
        wC[k] = *(const float2*)(Wb + (size_t)(eC[k] >> 16) * NN);

    for (unsigned j = 8; j < nrow8; j += 8) {
        unsigned eN[8];
        float2   wN[8];
        #pragma unroll
        for (int k = 0; k < 8; ++k) eN[k] = sc[j + k];
        #pragma unroll
        for (int k = 0; k < 8; ++k)
            wN[k] = *(const float2*)(Wb + (size_t)(eN[k] >> 16) * NN);
        #pragma unroll
        for (int k = 0; k < 8; ++k) bitacc(acc, eC[k], wC[k]);
        #pragma unroll
        for (int k = 0; k < 8; ++k) { eC[k] = eN[k]; wC[k] = wN[k]; }
    }
    #pragma unroll
    for (int k = 0; k < 8; ++k) bitacc(acc, eC[k], wC[k]);  // final group

    float* p = part + (size_t)y * BN + n;
    #pragma unroll
    for (int b = 0; b < BB; ++b)
        *(float2*)(p + (size_t)b * NN) = acc[b];
}

// ---------------------------------------------------------------------------
// k_fin: fused ALIF elementwise + partial reduction.
// out layout: [X (BN) | V_new (BN) | a_new (BN) | Xd_new (8*BN)]
// ---------------------------------------------------------------------------
__global__ __launch_bounds__(256) void k_fin(
    const float* __restrict__ V, const float* __restrict__ a,
    const float* __restrict__ part, float* __restrict__ out)
{
    const int t4 = blockIdx.x * 256 + threadIdx.x;  // [0, BN/4)

    float4 s = make_float4(0.f, 0.f, 0.f, 0.f);
    #pragma unroll 8
    for (int c = 0; c < NCH; ++c) {
        const float4 p = ((const float4*)(part + (size_t)c * BN))[t4];
        s.x += p.x; s.y += p.y; s.z += p.z; s.w += p.w;
    }

    const float4 v4 = ((const float4*)V)[t4];
    const float4 a4 = ((const float4*)a)[t4];
    float4 x4, vn4, an4;
    {
        const float* vv = &v4.x; const float* aa = &a4.x;
        float* xx = &x4.x; float* vn = &vn4.x; float* an = &an4.x;
        const float* ss = &s.x;
        #pragma unroll
        for (int k = 0; k < 4; ++k) {
            // exactness-critical: no FMA contraction on the threshold compare
            const float th = __fadd_rn(1.0f, __fmul_rn(1.8f, aa[k]));
            const bool spike = (vv[k] >= th);
            const float x = spike ? 1.0f : 0.0f;
            xx[k] = x;
            float v_new = spike ? 0.0f : __fmul_rn(ALPHA_F, vv[k]);
            vn[k] = __builtin_fmaf(SCALE_F, ss[k], v_new);
            an[k] = __fadd_rn(__fmul_rn(RHOA_F, aa[k]), x);
        }
    }
    ((float4*)out)[t4]                  = x4;   // X
    ((float4*)(out + (size_t)BN))[t4]   = vn4;  // V_new
    ((float4*)(out + (size_t)2*BN))[t4] = an4;  // a_new
    ((float4*)(out + (size_t)3*BN))[t4] = x4;   // Xd_new[0]
}

// ---------------------------------------------------------------------------
extern "C" void kernel_launch(void* const* d_in, const int* in_sizes, int n_in,
                              void* d_out, int out_size, void* d_ws, size_t ws_size,
                              hipStream_t stream)
{
    const float* V    = (const float*)d_in[0];
    const float* a    = (const float*)d_in[1];
    const float* Xd   = (const float*)d_in[2];
    const float* Xext = (const float*)d_in[3];
    const float* Wint = (const float*)d_in[4];
    const float* Wext = (const float*)d_in[5];
    float* out = (float*)d_out;

    unsigned* mask_int = (unsigned*)d_ws;                    // 8192 u32
    unsigned* mask_ext = mask_int + NN;                      // 4096 u32
    float*    part     = (float*)((char*)d_ws + 65536);      // NCH*BN f32 (12.6 MB)

    k_aux<<<(7*BN/4)/256, 256, 0, stream>>>(Xd, Xext, out, mask_int, mask_ext);
    k_mm<<<dim3(16, NCH), 256, 0, stream>>>(Wint, Wext, mask_int, mask_ext, part);
    k_fin<<<BN/4/256, 256, 0, stream>>>(V, a, part, out);
}